// Round 11
// baseline (26444.214 us; speedup 1.0000x reference)
//
#include <hip/hip_runtime.h>
#include <hip/hip_fp16.h>

#define T_LEN 65536
#define FDIM  128
#define NGATE 512   // 4*F for layer-2 LSTM
#define CH    16    // scan chunk (steps per LDS staging buffer)

typedef int iv4 __attribute__((ext_vector_type(4)));

// ---------- fast math helpers ----------
__device__ __forceinline__ float frcp(float x) { return __builtin_amdgcn_rcpf(x); }
#define LOG2E 1.4426950408889634f
__device__ __forceinline__ float sigmoid_f(float x) {
  return frcp(1.f + __builtin_amdgcn_exp2f(-LOG2E * x));
}

// ---------- DPP cross-lane reduce (Phase A/C only) ----------
template<int CTRL, int ROWM, int BANKM, bool BC>
__device__ __forceinline__ float dpp_mov0(float x) {
  return __int_as_float(
      __builtin_amdgcn_update_dpp(0, __float_as_int(x), CTRL, ROWM, BANKM, BC));
}
__device__ __forceinline__ float red8(float a) {
  a += dpp_mov0<0xB1, 0xF, 0xF, true>(a);   // quad_perm xor-1
  a += dpp_mov0<0x4E, 0xF, 0xF, true>(a);   // quad_perm xor-2
  a += dpp_mov0<0x114, 0xF, 0xA, true>(a);  // row_shr:4, banks 1&3
  return a;
}
__device__ __forceinline__ float red16(float a) {
  a += dpp_mov0<0x111, 0xF, 0xF, true>(a);
  a += dpp_mov0<0x112, 0xF, 0xF, true>(a);
  a += dpp_mov0<0x114, 0xF, 0xF, true>(a);
  a += dpp_mov0<0x118, 0xF, 0xF, true>(a);
  return a;
}

union H8  { uint4 u; __half h[8]; };
union G2u { uint2 u2; __half h[4]; };

// barrier draining ONLY lgkm (LDS): no per-step vmcnt round-trip.
#define LDS_BARRIER() asm volatile("s_waitcnt lgkmcnt(0)\n\ts_barrier" ::: "memory")

// ---------------------------------------------------------------------------
// Phase A: per-unit gate precompute, stored as [T][128] x {i,f,g,o} f16 quads.
// Stored values PRE-SCALED by the sigmoid/tanh exp2 multipliers
//   {-log2e, -log2e, -2log2e, -log2e}; dequant scales carry the same factors.
// ---------------------------------------------------------------------------
__global__ __launch_bounds__(512, 2)
void gx_kernel(const float* __restrict__ x, const float* __restrict__ Wih2,
               const float* __restrict__ bih2, const float* __restrict__ bhh2,
               __half* __restrict__ gx)
{
  __shared__ float xs[64 * FDIM];           // 32 KB tile of x
  const int tid  = threadIdx.x;
  const int lane = tid & 63;
  const int wave = tid >> 6;
  const int q    = lane & 7;
  const int pl   = lane >> 3;
  const int p    = wave * 8 + pl;
  const int u0   = 2 * p;

  float w[8][16];
  float bias[8];
#pragma unroll
  for (int j = 0; j < 8; ++j) {
    const int row = ((j >> 1) * 128) + u0 + (j & 1);   // j = {i0,i1,f0,f1,g0,g1,o0,o1}
    const int base = row * FDIM + q * 16;
#pragma unroll
    for (int k = 0; k < 16; ++k) w[j][k] = Wih2[base + k];
    bias[j] = bih2[row] + bhh2[row];
  }

  const int t0 = blockIdx.x * 64;
  const float4* xg = (const float4*)(x + (size_t)t0 * FDIM);
  float4* xs4 = (float4*)xs;
#pragma unroll
  for (int i = 0; i < 4; ++i) xs4[tid + i * 512] = xg[tid + i * 512];
  __syncthreads();

  for (int tt = 0; tt < 64; ++tt) {
    float hv[16];
    const float4* hv4 = (const float4*)(xs + tt * FDIM + q * 16);
    *(float4*)&hv[0]  = hv4[0];
    *(float4*)&hv[4]  = hv4[1];
    *(float4*)&hv[8]  = hv4[2];
    *(float4*)&hv[12] = hv4[3];

    float acc[8];
#pragma unroll
    for (int j = 0; j < 8; ++j) {
      float a = 0.f;
#pragma unroll
      for (int k = 0; k < 16; ++k) a = fmaf(w[j][k], hv[k], a);
      acc[j] = red8(a) + bias[j];
    }
    if (q == 4) {
      // unit-major gate quads, pre-scaled: i,f,o by -L; g by -2L
      const float mL = -LOG2E, m2L = -2.f * LOG2E;
      H8 pk;
      pk.h[0] = __float2half(acc[0] * mL);  pk.h[1] = __float2half(acc[2] * mL);
      pk.h[2] = __float2half(acc[4] * m2L); pk.h[3] = __float2half(acc[6] * mL);
      pk.h[4] = __float2half(acc[1] * mL);  pk.h[5] = __float2half(acc[3] * mL);
      pk.h[6] = __float2half(acc[5] * m2L); pk.h[7] = __float2half(acc[7] * mL);
      *((uint4*)(gx + ((size_t)(t0 + tt) * FDIM + u0) * 4)) = pk.u;
    }
  }
}

// ---------------------------------------------------------------------------
// Phase B: sequential LSTM-2 scan, DUAL-ENGINE. 256 threads, 4 waves (1/SIMD).
//   Gates {i,f,o} on the MATRIX pipe: 12 MFMAs/wave (3 gates x 2 col-chains
//   x 2 k), int8 B-fragments resident, broadcast-A = h.
//   Gate {g} on the VALU: each lane owns its unit's full W_hh2 g-row
//   (128 int8 in 32 VGPRs), 32x sdot4 issued AFTER the MFMAs -> executes on
//   the VALU concurrently with the matrix pipe (in-order legal), done before
//   the MFMA accs arrive. No cross-lane exchange: the lane that runs unit
//   u's tail computes g(u) itself.
// Same int8 per-row quantization + exact int32 accumulate for all 4 gates.
// Chunked LDS staging for gx and hist exactly as round 9/10.
// ---------------------------------------------------------------------------
__global__ __launch_bounds__(256)
void scan_kernel(const __half* __restrict__ gx, const float* __restrict__ Whh2,
                 const float* __restrict__ h20, const float* __restrict__ c20,
                 float* __restrict__ hist)
{
  __shared__ __align__(16) signed char hq[2][FDIM];     // 256 B  int8 h
  __shared__ __align__(16) char  gxl[2][CH * 1024];     // 32 KB staged gates
  __shared__ __align__(16) float histb[2][CH * FDIM];   // 16 KB h history

  const int tid  = threadIdx.x;
  const int lane = tid & 63;
  const int wave = tid >> 6;      // 0..3
  const int n    = lane & 15;     // MFMA column
  const int jg   = lane >> 4;     // k-subgroup (0..3)
  const int X    = jg & 1;        // which chain this lane's gate-math uses
  const int ul   = lane & 31;
  const int u    = 32 * wave + ul;   // unit for gate math (lanes 32-63 duplicate)

  const int GM[3] = {0, 1, 3};    // MFMA gates: i, f, o (g goes to VALU)

  // ---- init pass 1: per-row |W| maxima for MFMA gates (scratch on histb) ----
  float* smax = &histb[0][0];                 // 3*2*4*16*4 = 1536 floats
#pragma unroll
  for (int Xc = 0; Xc < 2; ++Xc) {
    const int urow = 32 * wave + 16 * Xc + n;
#pragma unroll
    for (int jj = 0; jj < 3; ++jj) {
      const float* wr = Whh2 + (size_t)(GM[jj] * FDIM + urow) * FDIM + 16 * jg;
      float m = 0.f;
#pragma unroll
      for (int kc = 0; kc < 2; ++kc)
#pragma unroll
        for (int j = 0; j < 16; ++j)
          m = fmaxf(m, fabsf(wr[64 * kc + j]));
      smax[((((wave * 2 + Xc) * 3 + jj) * 16) + n) * 4 + jg] = m;
    }
  }
  __syncthreads();

  // ---- init pass 2a: quantize {i,f,o} W into resident int8 B-fragments ----
  iv4 bq[2][3][2];          // [chain X][gate jj][k-chunk]
  float scC[2][3];
#pragma unroll
  for (int Xc = 0; Xc < 2; ++Xc) {
    const int urow = 32 * wave + 16 * Xc + n;
#pragma unroll
    for (int jj = 0; jj < 3; ++jj) {
      const int rowid = (((wave * 2 + Xc) * 3 + jj) * 16) + n;
      float s = fmaxf(fmaxf(smax[rowid * 4 + 0], smax[rowid * 4 + 1]),
                      fmaxf(smax[rowid * 4 + 2], smax[rowid * 4 + 3]));
      s = fmaxf(s, 1e-20f);
      scC[Xc][jj] = s * (1.f / 16129.f);
      const float inv = 127.f / s;
      const float* wr = Whh2 + (size_t)(GM[jj] * FDIM + urow) * FDIM + 16 * jg;
#pragma unroll
      for (int kc = 0; kc < 2; ++kc) {
        iv4 frag;
#pragma unroll
        for (int r = 0; r < 4; ++r) {
          int packed = 0;
#pragma unroll
          for (int b = 0; b < 4; ++b) {
            int qv = (int)rintf(wr[64 * kc + 4 * r + b] * inv);
            qv = qv < -127 ? -127 : (qv > 127 ? 127 : qv);
            packed |= (qv & 255) << (8 * b);
          }
          frag[r] = packed;
        }
        bq[Xc][jj][kc] = frag;
      }
    }
  }

  // ---- init pass 2b: quantize this lane's unit's g-row for VALU sdot ----
  int   wg[32];
  float dqg;
  {
    const float* wr = Whh2 + (size_t)(2 * FDIM + u) * FDIM;  // g-gate row of u
    float m = 1e-20f;
#pragma unroll
    for (int k = 0; k < FDIM; k += 4) {
      const float4 v = *(const float4*)(wr + k);
      m = fmaxf(m, fmaxf(fmaxf(fabsf(v.x), fabsf(v.y)),
                         fmaxf(fabsf(v.z), fabsf(v.w))));
    }
    const float inv = 127.f / m;
    dqg = m * (1.f / 16129.f) * (-2.f * LOG2E);   // fold tanh exp2 multiplier
#pragma unroll
    for (int d = 0; d < 32; ++d) {
      const float4 v = *(const float4*)(wr + 4 * d);
      int b0 = (int)rintf(v.x * inv), b1 = (int)rintf(v.y * inv);
      int b2 = (int)rintf(v.z * inv), b3 = (int)rintf(v.w * inv);
      b0 = b0 < -127 ? -127 : (b0 > 127 ? 127 : b0);
      b1 = b1 < -127 ? -127 : (b1 > 127 ? 127 : b1);
      b2 = b2 < -127 ? -127 : (b2 > 127 ? 127 : b2);
      b3 = b3 < -127 ? -127 : (b3 > 127 ? 127 : b3);
      wg[d] = (b0 & 255) | ((b1 & 255) << 8) | ((b2 & 255) << 16) | ((b3 & 255) << 24);
    }
  }

  // per-lane dequant scales for {i,f,o} with -log2e folded in
  float scl[3];
#pragma unroll
  for (int jj = 0; jj < 3; ++jj)
    scl[jj] = (X ? scC[1][jj] : scC[0][jj]) * (-LOG2E);

  float c = c20[u];
  if (tid < FDIM) {
    const float hv = fminf(fmaxf(h20[tid], -1.f), 1.f);
    hq[0][tid] = (signed char)(int)rintf(127.f * hv);
  }

  // preload gx chunk 0 into gxl[0]
  const uint4* gglob = (const uint4*)gx;      // 1024 uint4 per chunk
#pragma unroll
  for (int r = 0; r < 4; ++r) {
    const uint4 v = gglob[r * 256 + tid];
    *(uint4*)(&gxl[0][r * 4096 + tid * 16]) = v;
  }

  const iv4 zero = {0, 0, 0, 0};
  __syncthreads();        // seals smax scratch, hq[0], gxl[0]

  for (int t4 = 0; t4 < T_LEN; t4 += CH) {
    const int chunk = t4 >> 4;
    const int buf   = chunk & 1;

    // prefetch next gx chunk into registers (relayed to LDS at chunk end)
    const int nchunk = (chunk + 1) & (T_LEN / CH - 1);
    const uint4 pf0 = gglob[(size_t)nchunk * 1024 + 0 * 256 + tid];
    const uint4 pf1 = gglob[(size_t)nchunk * 1024 + 1 * 256 + tid];
    const uint4 pf2 = gglob[(size_t)nchunk * 1024 + 2 * 256 + tid];
    const uint4 pf3 = gglob[(size_t)nchunk * 1024 + 3 * 256 + tid];

    // flush previous chunk's h history (fire-and-forget)
    if (t4 != 0) {
      float* gdst = hist + (size_t)(t4 - CH) * FDIM;
      const float* hsb = &histb[1 - buf][0];
#pragma unroll
      for (int j = 0; j < 2; ++j) {
        const float4 v = *(const float4*)(hsb + 4 * (tid + 256 * j));
        *(float4*)(gdst + 4 * (tid + 256 * j)) = v;
      }
    }

#pragma unroll
    for (int s = 0; s < CH; ++s) {
      const signed char* hrow = hq[s & 1];

      // h_{t-1}: full 128 B broadcast (8x b128) + this lane's A-frags (2x b128)
      iv4 hv[8];
#pragma unroll
      for (int r = 0; r < 8; ++r)
        hv[r] = *(const iv4*)(hrow + 16 * r);
      const iv4 a0 = *(const iv4*)(hrow + jg * 16);
      const iv4 a1 = *(const iv4*)(hrow + 64 + jg * 16);
      G2u gg; gg.u2 = *(const uint2*)(&gxl[buf][s * 1024 + u * 8]);

      // 12 MFMA: 6 independent leads, then 6 dependents -> matrix pipe busy
      iv4 acc[2][3];
      {
        iv4 d00 = __builtin_amdgcn_mfma_i32_16x16x64_i8(a0, bq[0][0][0], zero, 0, 0, 0);
        iv4 d01 = __builtin_amdgcn_mfma_i32_16x16x64_i8(a0, bq[0][1][0], zero, 0, 0, 0);
        iv4 d02 = __builtin_amdgcn_mfma_i32_16x16x64_i8(a0, bq[0][2][0], zero, 0, 0, 0);
        iv4 d10 = __builtin_amdgcn_mfma_i32_16x16x64_i8(a0, bq[1][0][0], zero, 0, 0, 0);
        iv4 d11 = __builtin_amdgcn_mfma_i32_16x16x64_i8(a0, bq[1][1][0], zero, 0, 0, 0);
        iv4 d12 = __builtin_amdgcn_mfma_i32_16x16x64_i8(a0, bq[1][2][0], zero, 0, 0, 0);
        acc[0][0] = __builtin_amdgcn_mfma_i32_16x16x64_i8(a1, bq[0][0][1], d00, 0, 0, 0);
        acc[0][1] = __builtin_amdgcn_mfma_i32_16x16x64_i8(a1, bq[0][1][1], d01, 0, 0, 0);
        acc[0][2] = __builtin_amdgcn_mfma_i32_16x16x64_i8(a1, bq[0][2][1], d02, 0, 0, 0);
        acc[1][0] = __builtin_amdgcn_mfma_i32_16x16x64_i8(a1, bq[1][0][1], d10, 0, 0, 0);
        acc[1][1] = __builtin_amdgcn_mfma_i32_16x16x64_i8(a1, bq[1][1][1], d11, 0, 0, 0);
        acc[1][2] = __builtin_amdgcn_mfma_i32_16x16x64_i8(a1, bq[1][2][1], d12, 0, 0, 0);
      }

      // g-gate on the VALU while the matrix pipe crunches (in-order: these
      // issue after the MFMAs and need only hv/wg, not the accs)
      int s0 = 0, s1 = 0, s2 = 0, s3 = 0;
#pragma unroll
      for (int r = 0; r < 8; ++r) {
        s0 = __builtin_amdgcn_sdot4(wg[4 * r + 0], hv[r].x, s0, false);
        s1 = __builtin_amdgcn_sdot4(wg[4 * r + 1], hv[r].y, s1, false);
        s2 = __builtin_amdgcn_sdot4(wg[4 * r + 2], hv[r].z, s2, false);
        s3 = __builtin_amdgcn_sdot4(wg[4 * r + 3], hv[r].w, s3, false);
      }
      const int iaccg = (s0 + s1) + (s2 + s3);
      const float ag  = fmaf((float)iaccg, dqg, __half2float(gg.h[2]));
      const float tg  = fmaf(frcp(1.f + __builtin_amdgcn_exp2f(ag)), 2.f, -1.f);

      // tail: pick chains, one fma each, sigmoids
      const float dv0 = (float)(X ? acc[1][0][0] : acc[0][0][0]);
      const float dv1 = (float)(X ? acc[1][1][0] : acc[0][1][0]);
      const float dv2 = (float)(X ? acc[1][2][0] : acc[0][2][0]);
      const float ai = fmaf(dv0, scl[0], __half2float(gg.h[0]));
      const float af = fmaf(dv1, scl[1], __half2float(gg.h[1]));
      const float ao = fmaf(dv2, scl[2], __half2float(gg.h[3]));

      const float si = frcp(1.f + __builtin_amdgcn_exp2f(ai));
      const float sf = frcp(1.f + __builtin_amdgcn_exp2f(af));
      const float so = frcp(1.f + __builtin_amdgcn_exp2f(ao));

      c = fmaf(sf, c, si * tg);
      const float tc = fmaf(frcp(1.f + __builtin_amdgcn_exp2f(-2.f * LOG2E * c)),
                            2.f, -1.f);     // tanh(c)
      const float h = so * tc;

      // publish (duplicate lanes write identical values to the same address)
      hq[(s + 1) & 1][u] = (signed char)(int)rintf(127.f * h);
      histb[buf][s * FDIM + u] = h;

      if (s == CH - 1) {    // relay prefetched gx into the other LDS buffer
        *(uint4*)(&gxl[1 - buf][0 * 4096 + tid * 16]) = pf0;
        *(uint4*)(&gxl[1 - buf][1 * 4096 + tid * 16]) = pf1;
        *(uint4*)(&gxl[1 - buf][2 * 4096 + tid * 16]) = pf2;
        *(uint4*)(&gxl[1 - buf][3 * 4096 + tid * 16]) = pf3;
      }
      LDS_BARRIER();
    }
  }

  // final hist chunk flush (sealed by the loop's last barrier)
  {
    float* gdst = hist + (size_t)(T_LEN - CH) * FDIM;
    const float* hsb = &histb[1][0];
#pragma unroll
    for (int j = 0; j < 2; ++j) {
      const float4 v = *(const float4*)(hsb + 4 * (tid + 256 * j));
      *(float4*)(gdst + 4 * (tid + 256 * j)) = v;
    }
  }
}

// ---------------------------------------------------------------------------
// Phase C: out[t] = 2*sigmoid(W_fc @ h2[t] + b_fc), in place on d_out.
// ---------------------------------------------------------------------------
__global__ __launch_bounds__(512, 2)
void fc_kernel(const float* __restrict__ Wfc, const float* __restrict__ bfc,
               float* __restrict__ io)
{
  __shared__ float hs[64 * FDIM];
  const int tid  = threadIdx.x;
  const int lane = tid & 63;
  const int wave = tid >> 6;
  const int q    = lane & 15;
  const int gl   = lane >> 4;
  const int g    = wave * 4 + gl;           // 0..31

  float w[4][8];
#pragma unroll
  for (int r = 0; r < 4; ++r)
#pragma unroll
    for (int k = 0; k < 8; ++k)
      w[r][k] = Wfc[(4 * g + r) * FDIM + q * 8 + k];
  const float4 bias = ((const float4*)bfc)[g];

  const int t0 = blockIdx.x * 64;
  float4* iog = (float4*)(io + (size_t)t0 * FDIM);
  float4* hs4 = (float4*)hs;
#pragma unroll
  for (int i = 0; i < 4; ++i) hs4[tid + i * 512] = iog[tid + i * 512];
  __syncthreads();          // all reads of this block's rows done before writes

  for (int tt = 0; tt < 64; ++tt) {
    float hv[8];
    const float4* hv4 = (const float4*)(hs + tt * FDIM + q * 8);
    *(float4*)&hv[0] = hv4[0];
    *(float4*)&hv[4] = hv4[1];
    float acc[4];
#pragma unroll
    for (int r = 0; r < 4; ++r) {
      float a = 0.f;
#pragma unroll
      for (int k = 0; k < 8; ++k) a = fmaf(w[r][k], hv[k], a);
      acc[r] = red16(a);
    }
    if (q == 15) {
      float4 o;
      o.x = 2.f * sigmoid_f(acc[0] + bias.x);
      o.y = 2.f * sigmoid_f(acc[1] + bias.y);
      o.z = 2.f * sigmoid_f(acc[2] + bias.z);
      o.w = 2.f * sigmoid_f(acc[3] + bias.w);
      *(float4*)(io + (size_t)(t0 + tt) * FDIM + 4 * g) = o;
    }
  }
}

// ---------------------------------------------------------------------------
extern "C" void kernel_launch(void* const* d_in, const int* in_sizes, int n_in,
                              void* d_out, int out_size, void* d_ws, size_t ws_size,
                              hipStream_t stream) {
  const float* x    = (const float*)d_in[0];
  // d_in[1..2]: h1_0/c1_0  -- layer-1 LSTM never affects the output: skipped.
  const float* h20  = (const float*)d_in[3];
  const float* c20  = (const float*)d_in[4];
  // d_in[5..8]: W_ih1/W_hh1/b_ih1/b_hh1 -- dead.
  const float* Wih2 = (const float*)d_in[9];
  const float* Whh2 = (const float*)d_in[10];
  const float* bih2 = (const float*)d_in[11];
  const float* bhh2 = (const float*)d_in[12];
  const float* Wfc  = (const float*)d_in[13];
  const float* bfc  = (const float*)d_in[14];

  float*  out = (float*)d_out;              // [T,128]: h2 history, then final out
  __half* gx  = (__half*)d_ws;              // [T][128][4] f16 gate quads (64 MB)

  gx_kernel<<<T_LEN / 64, 512, 0, stream>>>(x, Wih2, bih2, bhh2, gx);
  scan_kernel<<<1, 256, 0, stream>>>(gx, Whh2, h20, c20, out);
  fc_kernel<<<T_LEN / 64, 512, 0, stream>>>(Wfc, bfc, out);
}